// Round 7
// baseline (289.330 us; speedup 1.0000x reference)
//
#include <hip/hip_runtime.h>
#include <math.h>

#define NPTS 512
#define NBATCH 64
#define NROWS (NPTS * NBATCH)   // 32768
#define LARGEV 1000000.0f
#define RPW 8                   // rows per wave in the MLP phases

typedef float v2f __attribute__((ext_vector_type(2)));

// acc = s*w + acc on both components (v_pk_fma_f32 when ISel can pack).
__device__ __forceinline__ void pk_fma(v2f& acc, float s, v2f w) {
  acc = __builtin_elementwise_fma(w, (v2f){s, s}, acc);
}

// ---------------------------------------------------------------------------
// Fully fused kernel: mask sniff + decode + pairwise features + MLP.
// Block = 256 threads = 32 rows x 8 j-chunks (feat) = 4 waves x 8 rows (MLP).
// Grid 1024. LDS ~27.3KB.
//
// Round-6 lessons applied:
// - sector scatter was a serial LDS RMW (compiler can't disprove aliasing of
//   dynamic addresses -> read_{n+1} ordered after write_n) with 4-way bank
//   conflicts (uint2 stride 18 words). Now: fire-and-forget atomicMin/Add
//   (ds_min_u32/ds_add_u32, no return -> no loop-carried dependency) on
//   [slot][tid] planes (bank = tid%32, conflict-free). u32-bit min is valid:
//   all real dists > 0; NaN dists (masked j / self) provably land in slot 8.
// - MLP readlane broadcasts (1288 VALU ops/thread) replaced by transposed
//   LDS staging (xsT/gT, row-stride 36 -> 16B-aligned) + wave-uniform
//   ds_read_b128 broadcasts on the DS pipe.
// - gT aliases the sector scratch (both 4608 words); one __syncthreads
//   between last scratch read and first gT write.
// - vcnt derived once per block from masked-count M (ballot) instead of
//   per-pair accumulation.
// __f*_rn keeps dist bit-identical to numpy (threshold compares exact).
// ---------------------------------------------------------------------------
__global__ __launch_bounds__(256, 4) void fused_kernel(const float* __restrict__ pos,
    const void* __restrict__ kpm,
    const float* __restrict__ W1, const float* __restrict__ b1,
    const float* __restrict__ gamma, const float* __restrict__ beta,
    const float* __restrict__ W2, const float* __restrict__ b2,
    float* __restrict__ out) {
  __shared__ float2 sp[NPTS];          //  4096 B
  __shared__ unsigned scru[2 * 9 * 256]; // 18432 B: [0]=min bits, [1]=count, [slot][tid]
  __shared__ float xsT[33 * 36];       //  4752 B: [k][row] feature transpose
  __shared__ int sflag, sMasked;
  float* __restrict__ gT = (float*)scru;   // 128*36 = 4608 floats, aliases scru

  const int b  = blockIdx.x >> 4;
  const int i0 = (blockIdx.x & 15) << 5;
  const int tid = threadIdx.x;

  // ---- inline mask-dtype sniff over first 2KB of the raw mask buffer ----
  if (tid == 0) { sflag = 0; sMasked = 0; }
  __syncthreads();
  {
    const unsigned int* rw = (const unsigned int*)kpm;
    const unsigned int w0 = rw[tid];
    const unsigned int w1 = rw[tid + 256];
    int f = 0;
    if (w0 == 0x3f800000u || w1 == 0x3f800000u) f |= 2;   // float 1.0 pattern
    if (w0 > 1u || w1 > 1u) f |= 1;                        // packed-byte pattern
    if (f) atomicOr(&sflag, f);
  }
  __syncthreads();
  const int fmt = sflag;   // 2=>f32, 1=>bytes, 0=>i32 (f32 priority)

  // ---- stage positions (NaN for masked), count masked via ballot ----
  for (int t = tid; t < NPTS; t += 256) {
    bool m;
    if (fmt & 2)      m = ((const float*)kpm)[b * NPTS + t] != 0.0f;
    else if (fmt & 1) m = ((const unsigned char*)kpm)[b * NPTS + t] != 0;
    else              m = ((const int*)kpm)[b * NPTS + t] != 0;
    float2 p = ((const float2*)pos)[b * NPTS + t];
    if (m) { p.x = __builtin_nanf(""); p.y = p.x; }
    sp[t] = p;
    unsigned long long bal = __ballot(m);
    if ((tid & 63) == 0) atomicAdd(&sMasked, __popcll(bal));
  }
  // per-thread scratch init (private cells -> no barrier needed vs own use)
#pragma unroll
  for (int k = 0; k < 9; ++k) {
    scru[k * 256 + tid] = __float_as_uint(LARGEV);
    scru[2304 + k * 256 + tid] = 0u;
  }
  __syncthreads();
  const int M = sMasked;

  const int il = tid >> 3;       // row within block: 0..31
  const int jc = tid & 7;        // j-chunk: 0..7
  const int i  = i0 + il;
  const float2 pi = ((const float2*)pos)[b * NPTS + i];   // real anchor (global)

  unsigned cu = 0u, cd = 0u, cl = 0u;   // packed counts: byte0=w3..byte3=w12
  float dmin0 = LARGEV, dmin1 = LARGEV, dmin2 = LARGEV;
  float sumd = 0.0f;

#pragma unroll 8
  for (int jj = 0; jj < 64; ++jj) {
    const int j = (jj << 3) + jc;
    const float2 pj = sp[j];
    const float dx = __fsub_rn(pj.x, pi.x);
    const float dy = __fsub_rn(pj.y, pi.y);
    const float d2 = __fadd_rn(__fadd_rn(__fmul_rn(dx, dx), __fmul_rn(dy, dy)), 1e-8f);
    float dist = __fsqrt_rn(d2);
    dist = (j == i) ? __builtin_nanf("") : dist;          // self -> NaN

    const float hdy = __fmul_rn(fabsf(dy), 0.5f);
    const bool up = dx > hdy;
    const bool dn = dx < -hdy;

    const bool w3  = dist <  3.0f;
    const bool w5  = dist <  5.0f;
    const bool w8  = dist <  8.0f;
    const bool w12 = dist < 12.0f;
    const unsigned a = w3 ? 0x01010101u
                     : (w5 ? 0x01010100u
                     : (w8 ? 0x01010000u
                     : (w12 ? 0x01000000u : 0u)));
    cu += up ? a : 0u;
    cd += dn ? a : 0u;
    cl += (!up && !dn) ? a : 0u;

    dmin0 = fminf(dmin0, up ? dist : LARGEV);
    dmin1 = fminf(dmin1, dn ? dist : LARGEV);
    dmin2 = fminf(dmin2, (!up && !dn) ? dist : LARGEV);   // NaN dropped (minNum)

    sumd += (dist < 1.0e30f) ? dist : 0.0f;               // NaN -> false

    // octant sector; dy==0,dx>0 -> s4 (angle 0); dy==0,dx<=0 / NaN -> 8
    const int slot = (dy > 0.0f)
        ? ((dx > 0.0f) ? ((dy < dx) ? 4 : 5) : ((-dx < dy) ? 6 : 7))
        : ((dy < 0.0f) ? ((dx < 0.0f) ? ((dx < dy) ? 0 : 1) : ((dx < -dy) ? 2 : 3))
                       : ((dx > 0.0f) ? 4 : 8));
    const int idx = slot * 256 + tid;
    atomicMin(&scru[idx], __float_as_uint(dist));   // ds_min_u32, no return
    atomicAdd(&scru[2304 + idx], 1u);               // ds_add_u32, no return
  }

  // ---- readback per-thread sector slots (in-wave DS order) + unpack ----
  float cnt[12];
  cnt[0] = (float)(cu & 0xffu);  cnt[3] = (float)((cu >> 8) & 0xffu);
  cnt[6] = (float)((cu >> 16) & 0xffu);  cnt[9]  = (float)(cu >> 24);
  cnt[1] = (float)(cd & 0xffu);  cnt[4] = (float)((cd >> 8) & 0xffu);
  cnt[7] = (float)((cd >> 16) & 0xffu);  cnt[10] = (float)(cd >> 24);
  cnt[2] = (float)(cl & 0xffu);  cnt[5] = (float)((cl >> 8) & 0xffu);
  cnt[8] = (float)((cl >> 16) & 0xffu);  cnt[11] = (float)(cl >> 24);
  float scnt[8], smin[8];
#pragma unroll
  for (int k = 0; k < 8; ++k) {
    smin[k] = __uint_as_float(scru[k * 256 + tid]);
    scnt[k] = (float)scru[2304 + k * 256 + tid];
  }
  float dmin[3] = {dmin0, dmin1, dmin2};

  // ---- reduce 8 chunk partials (lanes differing in bits 0..2) ----
#pragma unroll
  for (int k = 0; k < 12; ++k) {
    cnt[k] += __shfl_xor(cnt[k], 1); cnt[k] += __shfl_xor(cnt[k], 2); cnt[k] += __shfl_xor(cnt[k], 4);
  }
#pragma unroll
  for (int k = 0; k < 8; ++k) {
    scnt[k] += __shfl_xor(scnt[k], 1); scnt[k] += __shfl_xor(scnt[k], 2); scnt[k] += __shfl_xor(scnt[k], 4);
  }
  sumd += __shfl_xor(sumd, 1); sumd += __shfl_xor(sumd, 2); sumd += __shfl_xor(sumd, 4);
#pragma unroll
  for (int k = 0; k < 3; ++k) {
    dmin[k] = fminf(dmin[k], __shfl_xor(dmin[k], 1));
    dmin[k] = fminf(dmin[k], __shfl_xor(dmin[k], 2));
    dmin[k] = fminf(dmin[k], __shfl_xor(dmin[k], 4));
  }
#pragma unroll
  for (int k = 0; k < 8; ++k) {
    smin[k] = fminf(smin[k], __shfl_xor(smin[k], 1));
    smin[k] = fminf(smin[k], __shfl_xor(smin[k], 2));
    smin[k] = fminf(smin[k], __shfl_xor(smin[k], 4));
  }

  // ---- write row il's 33 feats transposed: xsT[k][il] ----
  if (jc == 0) {
    const bool own_unmasked = !isnan(sp[i].x);
    const float vcnt = fmaxf((float)(NPTS - M - (own_unmasked ? 1 : 0)), 1.0f);
#pragma unroll
    for (int k = 0; k < 12; ++k) xsT[k * 36 + il] = cnt[k];
    xsT[12 * 36 + il] = fminf(dmin[0] * 0.1f, 1.0f);
    xsT[13 * 36 + il] = fminf(dmin[1] * 0.1f, 1.0f);
    xsT[14 * 36 + il] = fminf(dmin[2] * 0.1f, 1.0f);
#pragma unroll
    for (int k = 0; k < 8; ++k) {
      xsT[(15 + 2 * k) * 36 + il] = scnt[k];
      xsT[(16 + 2 * k) * 36 + il] = fminf(smin[k] * 0.1f, 1.0f);
    }
    xsT[31 * 36 + il] = cnt[9] + cnt[10] + cnt[11];
    xsT[32 * 36 + il] = fminf(sumd / vcnt * 0.1f, 1.0f);
  }

  // all waves' scratch reads must complete before gT (aliased) is written
  __syncthreads();

  // ======================= MLP section =======================
  const int w = tid >> 6;
  const int l = tid & 63;
  const int r0 = RPW * w;                     // wave's first row in block

  const v2f b1v = ((const v2f*)b1)[l];
  const v2f gav = ((const v2f*)gamma)[l];
  const v2f bev = ((const v2f*)beta)[l];
  const v2f b2v = ((const v2f*)b2)[l];
  const v2f* __restrict__ W1v = (const v2f*)W1;
  const v2f* __restrict__ W2v = (const v2f*)W2;

  // ---- phase 1: h = x @ W1 + b1 (b128 broadcast of xsT rows) ----
  v2f h[RPW];
#pragma unroll
  for (int r = 0; r < RPW; ++r) h[r] = b1v;
#pragma unroll
  for (int k = 0; k < 33; ++k) {
    const v2f wv = W1v[k * 64 + l];
    const float4 xa = *(const float4*)&xsT[k * 36 + r0];
    const float4 xb = *(const float4*)&xsT[k * 36 + r0 + 4];
    pk_fma(h[0], xa.x, wv); pk_fma(h[1], xa.y, wv);
    pk_fma(h[2], xa.z, wv); pk_fma(h[3], xa.w, wv);
    pk_fma(h[4], xb.x, wv); pk_fma(h[5], xb.y, wv);
    pk_fma(h[6], xb.z, wv); pk_fma(h[7], xb.w, wv);
  }

  // ---- phase 2: LayerNorm + exact GELU; park g transposed in gT[k][row] ----
#pragma unroll
  for (int r = 0; r < RPW; ++r) {
    float s = h[r].x + h[r].y;
#pragma unroll
    for (int o = 32; o > 0; o >>= 1) s += __shfl_xor(s, o);
    const float mu = s * 0.0078125f;
    const float d0 = h[r].x - mu, d1 = h[r].y - mu;
    float v = d0 * d0 + d1 * d1;
#pragma unroll
    for (int o = 32; o > 0; o >>= 1) v += __shfl_xor(v, o);
    const float inv = 1.0f / __fsqrt_rn(v * 0.0078125f + 1e-5f);
    float a = d0 * inv * gav.x + bev.x;
    float bb = d1 * inv * gav.y + bev.y;
    gT[(2 * l) * 36 + r0 + r]     = 0.5f * a * (1.0f + erff(a * 0.70710678118654752f));
    gT[(2 * l + 1) * 36 + r0 + r] = 0.5f * bb * (1.0f + erff(bb * 0.70710678118654752f));
  }
  // gT rows r0..r0+7 written by this wave, read by this wave -> no barrier

  // ---- phase 3: out = g @ W2 + b2 (b128 broadcast of gT rows) ----
  v2f acc[RPW];
#pragma unroll
  for (int r = 0; r < RPW; ++r) acc[r] = b2v;
#pragma unroll 4
  for (int kp = 0; kp < 64; ++kp) {            // k = 2*kp, 2*kp+1
    const v2f wva = W2v[(2 * kp) * 64 + l];
    const v2f wvb = W2v[(2 * kp + 1) * 64 + l];
    const float4 ga = *(const float4*)&gT[(2 * kp) * 36 + r0];
    const float4 gb = *(const float4*)&gT[(2 * kp) * 36 + r0 + 4];
    const float4 ha = *(const float4*)&gT[(2 * kp + 1) * 36 + r0];
    const float4 hb = *(const float4*)&gT[(2 * kp + 1) * 36 + r0 + 4];
    pk_fma(acc[0], ga.x, wva); pk_fma(acc[1], ga.y, wva);
    pk_fma(acc[2], ga.z, wva); pk_fma(acc[3], ga.w, wva);
    pk_fma(acc[4], gb.x, wva); pk_fma(acc[5], gb.y, wva);
    pk_fma(acc[6], gb.z, wva); pk_fma(acc[7], gb.w, wva);
    pk_fma(acc[0], ha.x, wvb); pk_fma(acc[1], ha.y, wvb);
    pk_fma(acc[2], ha.z, wvb); pk_fma(acc[3], ha.w, wvb);
    pk_fma(acc[4], hb.x, wvb); pk_fma(acc[5], hb.y, wvb);
    pk_fma(acc[6], hb.z, wvb); pk_fma(acc[7], hb.w, wvb);
  }
  const int row0 = blockIdx.x * 32 + r0;
#pragma unroll
  for (int r = 0; r < RPW; ++r) {
    ((v2f*)out)[(size_t)(row0 + r) * 64 + l] = acc[r];
  }
}

extern "C" void kernel_launch(void* const* d_in, const int* in_sizes, int n_in,
                              void* d_out, int out_size, void* d_ws, size_t ws_size,
                              hipStream_t stream) {
  const float* positions = (const float*)d_in[0];
  const void*  kpm_raw   = d_in[1];
  const float* W1    = (const float*)d_in[2];
  const float* b1    = (const float*)d_in[3];
  const float* gamma = (const float*)d_in[4];
  const float* beta  = (const float*)d_in[5];
  const float* W2    = (const float*)d_in[6];
  const float* b2    = (const float*)d_in[7];
  float* out = (float*)d_out;

  fused_kernel<<<NBATCH * 16, 256, 0, stream>>>(positions, kpm_raw,
      W1, b1, gamma, beta, W2, b2, out);
}

// Round 8
// 142.807 us; speedup vs baseline: 2.0260x; 2.0260x over previous
//
#include <hip/hip_runtime.h>
#include <math.h>

#define NPTS 512
#define NBATCH 64
#define NROWS (NPTS * NBATCH)   // 32768
#define LARGEV 1000000.0f
#define RPW 8                   // rows per wave in the MLP phases

typedef float v2f __attribute__((ext_vector_type(2)));

__device__ __forceinline__ float rdlane(float v, int l) {
  return __uint_as_float((unsigned)__builtin_amdgcn_readlane((int)__float_as_uint(v), l));
}

// acc = s*w + acc on both components (v_pk_fma_f32 when ISel can pack).
__device__ __forceinline__ void pk_fma(v2f& acc, float s, v2f w) {
  acc = __builtin_elementwise_fma(w, (v2f){s, s}, acc);
}

// ---------------------------------------------------------------------------
// Fused kernel = round-6 structure (85us, verified) + ONE change:
// sector scatter now uses fire-and-forget DS atomics on [slot][tid] planes.
//  - round-6 defect: uint2 scr[tid*9+slot] RMW -> 4-way bank conflicts
//    (stride 18 words) + serialized load->min->store LDS chain (compiler
//    can't disprove aliasing of dynamic addresses).
//  - fix: atomicMin/atomicAdd on __shared__ (ds_min_u32/ds_add_u32, no
//    return -> no loop-carried dependency, no extra live registers);
//    planes scru[slot*256+tid] -> bank = tid%32 -> conflict-free.
//  - u32-bit min == float min for positive reals; NaN dists (masked j /
//    self) have compare-false on every branch -> provably slot 8 (trash).
// Round-7 lesson (DO NOT repeat): phase-1/3 LDS-transpose + float4
// broadcast restructure spilled to scratch (FETCH 400MB, WRITE 256MB,
// 227us). Keep the readlane MLP: VGPR=64, zero spill, VALU 70%.
// __f*_rn keeps dist bit-identical to numpy (threshold compares exact).
// ---------------------------------------------------------------------------
__global__ __launch_bounds__(256, 4) void fused_kernel(const float* __restrict__ pos,
    const void* __restrict__ kpm,
    const float* __restrict__ W1, const float* __restrict__ b1,
    const float* __restrict__ gamma, const float* __restrict__ beta,
    const float* __restrict__ W2, const float* __restrict__ b2,
    float* __restrict__ out) {
  __shared__ float2 sp[NPTS];            //  4096 B
  __shared__ unsigned scru[2 * 9 * 256]; // 18432 B: [0..8]=min bits, [9..17]=count, [slot][tid]
  __shared__ float xs[32 * 33];          //  4224 B  per-row feature vectors
  __shared__ int sflag;
  const int b  = blockIdx.x >> 4;
  const int i0 = (blockIdx.x & 15) << 5;
  const int tid = threadIdx.x;

  // ---- inline mask-dtype sniff over first 2KB of the raw mask buffer ----
  if (tid == 0) sflag = 0;
  __syncthreads();
  {
    const unsigned int* rw = (const unsigned int*)kpm;
    const unsigned int w0 = rw[tid];
    const unsigned int w1 = rw[tid + 256];
    int f = 0;
    if (w0 == 0x3f800000u || w1 == 0x3f800000u) f |= 2;   // float 1.0 pattern
    if (w0 > 1u || w1 > 1u) f |= 1;                        // packed-byte pattern
    if (f) atomicOr(&sflag, f);
  }
  __syncthreads();
  const int fmt = sflag;   // 2=>f32, 1=>bytes, 0=>i32 (f32 priority)

  // ---- stage positions, NaN-ifying masked points; init sector planes ----
  for (int t = tid; t < NPTS; t += 256) {
    bool m;
    if (fmt & 2)      m = ((const float*)kpm)[b * NPTS + t] != 0.0f;
    else if (fmt & 1) m = ((const unsigned char*)kpm)[b * NPTS + t] != 0;
    else              m = ((const int*)kpm)[b * NPTS + t] != 0;
    float2 p = ((const float2*)pos)[b * NPTS + t];
    if (m) { p.x = __builtin_nanf(""); p.y = p.x; }
    sp[t] = p;
  }
#pragma unroll
  for (int k = 0; k < 9; ++k) {
    scru[k * 256 + tid] = __float_as_uint(LARGEV);   // per-thread min cell
    scru[2304 + k * 256 + tid] = 0u;                 // per-thread count cell
  }
  __syncthreads();

  const int il = tid >> 3;       // row within block: 0..31
  const int jc = tid & 7;        // j-chunk: 0..7
  const int i  = i0 + il;
  const float2 pi = ((const float2*)pos)[b * NPTS + i];   // real anchor (global)

  unsigned cu = 0u, cd = 0u, cl = 0u;   // packed counts: byte0=w3..byte3=w12
  float dmin0 = LARGEV, dmin1 = LARGEV, dmin2 = LARGEV;
  float sumd = 0.0f;
  int vcn = 0;

#pragma unroll 4
  for (int jj = 0; jj < 64; ++jj) {
    const int j = (jj << 3) + jc;
    const float2 pj = sp[j];
    const float dx = __fsub_rn(pj.x, pi.x);
    const float dy = __fsub_rn(pj.y, pi.y);
    const float d2 = __fadd_rn(__fadd_rn(__fmul_rn(dx, dx), __fmul_rn(dy, dy)), 1e-8f);
    float dist = __fsqrt_rn(d2);
    dist = (j == i) ? __builtin_nanf("") : dist;          // self -> NaN

    const float hdy = __fmul_rn(fabsf(dy), 0.5f);
    const bool up = dx > hdy;
    const bool dn = dx < -hdy;

    const bool w3  = dist <  3.0f;
    const bool w5  = dist <  5.0f;
    const bool w8  = dist <  8.0f;
    const bool w12 = dist < 12.0f;
    const unsigned a = w3 ? 0x01010101u
                     : (w5 ? 0x01010100u
                     : (w8 ? 0x01010000u
                     : (w12 ? 0x01000000u : 0u)));
    cu += up ? a : 0u;
    cd += dn ? a : 0u;
    cl += (!up && !dn) ? a : 0u;

    dmin0 = fminf(dmin0, up ? dist : LARGEV);
    dmin1 = fminf(dmin1, dn ? dist : LARGEV);
    dmin2 = fminf(dmin2, (!up && !dn) ? dist : LARGEV);   // NaN dropped (minNum)

    const bool c = dist < 1.0e30f;                         // NaN -> false
    sumd += c ? dist : 0.0f;
    vcn  += c ? 1 : 0;

    // octant sector; dy==0,dx>0 -> s4 (angle 0); dy==0,dx<=0 / NaN -> 8
    const int slot = (dy > 0.0f)
        ? ((dx > 0.0f) ? ((dy < dx) ? 4 : 5) : ((-dx < dy) ? 6 : 7))
        : ((dy < 0.0f) ? ((dx < 0.0f) ? ((dx < dy) ? 0 : 1) : ((dx < -dy) ? 2 : 3))
                       : ((dx > 0.0f) ? 4 : 8));
    const int idx = slot * 256 + tid;
    atomicMin(&scru[idx], __float_as_uint(dist));   // ds_min_u32, no return
    atomicAdd(&scru[2304 + idx], 1u);               // ds_add_u32, no return
  }

  // ---- readback own sector cells (same-thread DS order) + unpack ----
  float cnt[12];
  cnt[0] = (float)(cu & 0xffu);  cnt[3] = (float)((cu >> 8) & 0xffu);
  cnt[6] = (float)((cu >> 16) & 0xffu);  cnt[9]  = (float)(cu >> 24);
  cnt[1] = (float)(cd & 0xffu);  cnt[4] = (float)((cd >> 8) & 0xffu);
  cnt[7] = (float)((cd >> 16) & 0xffu);  cnt[10] = (float)(cd >> 24);
  cnt[2] = (float)(cl & 0xffu);  cnt[5] = (float)((cl >> 8) & 0xffu);
  cnt[8] = (float)((cl >> 16) & 0xffu);  cnt[11] = (float)(cl >> 24);
  float scnt[8], smin[8];
#pragma unroll
  for (int k = 0; k < 8; ++k) {
    smin[k] = __uint_as_float(scru[k * 256 + tid]);
    scnt[k] = (float)scru[2304 + k * 256 + tid];
  }
  float vcnt = (float)vcn;
  float dmin[3] = {dmin0, dmin1, dmin2};

  // ---- reduce 8 chunk partials (lanes differing in bits 0..2) ----
#pragma unroll
  for (int k = 0; k < 12; ++k) {
    cnt[k] += __shfl_xor(cnt[k], 1); cnt[k] += __shfl_xor(cnt[k], 2); cnt[k] += __shfl_xor(cnt[k], 4);
  }
#pragma unroll
  for (int k = 0; k < 8; ++k) {
    scnt[k] += __shfl_xor(scnt[k], 1); scnt[k] += __shfl_xor(scnt[k], 2); scnt[k] += __shfl_xor(scnt[k], 4);
  }
  sumd += __shfl_xor(sumd, 1); sumd += __shfl_xor(sumd, 2); sumd += __shfl_xor(sumd, 4);
  vcnt += __shfl_xor(vcnt, 1); vcnt += __shfl_xor(vcnt, 2); vcnt += __shfl_xor(vcnt, 4);
#pragma unroll
  for (int k = 0; k < 3; ++k) {
    dmin[k] = fminf(dmin[k], __shfl_xor(dmin[k], 1));
    dmin[k] = fminf(dmin[k], __shfl_xor(dmin[k], 2));
    dmin[k] = fminf(dmin[k], __shfl_xor(dmin[k], 4));
  }
#pragma unroll
  for (int k = 0; k < 8; ++k) {
    smin[k] = fminf(smin[k], __shfl_xor(smin[k], 1));
    smin[k] = fminf(smin[k], __shfl_xor(smin[k], 2));
    smin[k] = fminf(smin[k], __shfl_xor(smin[k], 4));
  }

  // ---- park row il's 33 feats in LDS (writer lane il*8 is in the same wave
  //      that consumes rows 8w..8w+7 below -> no barrier needed) ----
  if (jc == 0) {
    float* f = &xs[il * 33];
#pragma unroll
    for (int k = 0; k < 12; ++k) f[k] = cnt[k];
    f[12] = fminf(dmin[0] * 0.1f, 1.0f);
    f[13] = fminf(dmin[1] * 0.1f, 1.0f);
    f[14] = fminf(dmin[2] * 0.1f, 1.0f);
#pragma unroll
    for (int k = 0; k < 8; ++k) {
      f[15 + 2 * k] = scnt[k];
      f[16 + 2 * k] = fminf(smin[k] * 0.1f, 1.0f);
    }
    f[31] = cnt[9] + cnt[10] + cnt[11];
    f[32] = fminf(sumd / fmaxf(vcnt, 1.0f) * 0.1f, 1.0f);
  }

  // ======================= MLP section (round-6, unchanged) ===============
  const int w = tid >> 6;
  const int l = tid & 63;
  const float* __restrict__ xsf = xs + w * (RPW * 33);   // wave's 264 floats

  float xreg[5];
#pragma unroll
  for (int c = 0; c < 4; ++c) xreg[c] = xsf[c * 64 + l];
  xreg[4] = (l < 8) ? xsf[256 + l] : 0.0f;

  const v2f b1v = ((const v2f*)b1)[l];
  const v2f gav = ((const v2f*)gamma)[l];
  const v2f bev = ((const v2f*)beta)[l];
  const v2f b2v = ((const v2f*)b2)[l];
  const v2f* __restrict__ W1v = (const v2f*)W1;
  const v2f* __restrict__ W2v = (const v2f*)W2;

  // ---- phase 1: h = x @ W1 + b1 (readlane broadcast + packed fma) ----
  v2f h[RPW];
#pragma unroll
  for (int r = 0; r < RPW; ++r) h[r] = b1v;
#pragma unroll
  for (int k = 0; k < 33; ++k) {
    const v2f wv = W1v[k * 64 + l];
#pragma unroll
    for (int r = 0; r < RPW; ++r) {
      const int v = r * 33 + k;                 // compile-time
      pk_fma(h[r], rdlane(xreg[v >> 6], v & 63), wv);
    }
  }

  // ---- phase 2: LayerNorm + exact GELU (in registers) ----
  float g0[RPW], g1[RPW];
#pragma unroll
  for (int r = 0; r < RPW; ++r) {
    float s = h[r].x + h[r].y;
#pragma unroll
    for (int o = 32; o > 0; o >>= 1) s += __shfl_xor(s, o);
    const float mu = s * 0.0078125f;
    const float d0 = h[r].x - mu, d1 = h[r].y - mu;
    float v = d0 * d0 + d1 * d1;
#pragma unroll
    for (int o = 32; o > 0; o >>= 1) v += __shfl_xor(v, o);
    const float inv = 1.0f / __fsqrt_rn(v * 0.0078125f + 1e-5f);
    float a = d0 * inv * gav.x + bev.x;
    float bb = d1 * inv * gav.y + bev.y;
    g0[r] = 0.5f * a * (1.0f + erff(a * 0.70710678118654752f));
    g1[r] = 0.5f * bb * (1.0f + erff(bb * 0.70710678118654752f));
  }

  // ---- phase 3: out = g @ W2 + b2 (readlane broadcast + packed fma) ----
  v2f acc[RPW];
#pragma unroll
  for (int r = 0; r < RPW; ++r) acc[r] = b2v;
#pragma unroll 8
  for (int kp = 0; kp < 64; ++kp) {            // k = 2*kp, 2*kp+1
    const v2f wva = W2v[(2 * kp) * 64 + l];
    const v2f wvb = W2v[(2 * kp + 1) * 64 + l];
#pragma unroll
    for (int r = 0; r < RPW; ++r) {
      pk_fma(acc[r], rdlane(g0[r], kp), wva);
      pk_fma(acc[r], rdlane(g1[r], kp), wvb);
    }
  }
  const int row0 = blockIdx.x * 32 + RPW * w;  // == b*512 + i0 + w*8
#pragma unroll
  for (int r = 0; r < RPW; ++r) {
    ((v2f*)out)[(size_t)(row0 + r) * 64 + l] = acc[r];
  }
}

extern "C" void kernel_launch(void* const* d_in, const int* in_sizes, int n_in,
                              void* d_out, int out_size, void* d_ws, size_t ws_size,
                              hipStream_t stream) {
  const float* positions = (const float*)d_in[0];
  const void*  kpm_raw   = d_in[1];
  const float* W1    = (const float*)d_in[2];
  const float* b1    = (const float*)d_in[3];
  const float* gamma = (const float*)d_in[4];
  const float* beta  = (const float*)d_in[5];
  const float* W2    = (const float*)d_in[6];
  const float* b2    = (const float*)d_in[7];
  float* out = (float*)d_out;

  fused_kernel<<<NBATCH * 16, 256, 0, stream>>>(positions, kpm_raw,
      W1, b1, gamma, beta, W2, b2, out);
}